// Round 13
// baseline (192.008 us; speedup 1.0000x reference)
//
#include <hip/hip_runtime.h>
#include <hip/hip_fp16.h>

#define F_IN 128
#define HID  64
#define NCLS 16
#define NPB  128      // nodes per bucket (pow2); bucket = col >> 7
#define CAP  4096     // edge slots reserved per bucket (2x mean 2046; ~45 sigma)
#define CHUNK 4096    // edges per phaseA block (= 4 * BINTHREADS exactly)
#define BINTHREADS 1024

typedef _Float16 half_t;
typedef __attribute__((ext_vector_type(8))) _Float16 half8;
typedef __attribute__((ext_vector_type(4))) float float4v;

// ---------------- phase A: bin edges into capped bucket regions + (fused) W1 prep ----------------
// 4 edges/thread held in registers across both passes (no second col read).
// Region base for bucket b = b*CAP. Payload packed (row<<7 | local_col).
// Block nblkE converts W1 f32 [128][64] -> f16 transposed [64][128].

__global__ __launch_bounds__(BINTHREADS) void phaseA(
    const int* __restrict__ row, const int* __restrict__ col,
    int* __restrict__ cursor, int* __restrict__ ebuf, int E, int NB,
    const float* __restrict__ W1, half_t* __restrict__ W1t, int nblkE)
{
    if ((int)blockIdx.x >= nblkE) {               // W1 prep block
        for (int i = threadIdx.x; i < F_IN * HID; i += BINTHREADS) {
            int k = i >> 6, n = i & 63;
            W1t[n * F_IN + k] = (half_t)W1[i];
        }
        return;
    }
    __shared__ int hist[1024], base[1024], off[1024];   // NB <= 1024
    for (int i = threadIdx.x; i < NB; i += BINTHREADS) hist[i] = 0;
    int e0 = blockIdx.x * CHUNK + threadIdx.x * 4;
    int nv = min(max(E - e0, 0), 4);              // valid edges this thread
    int4 c4 = make_int4(0, 0, 0, 0), r4 = make_int4(0, 0, 0, 0);
    if (nv == 4) {                                // 16B-aligned fast path
        c4 = *(const int4*)&col[e0];
        r4 = *(const int4*)&row[e0];
    } else {
        if (nv > 0) { c4.x = col[e0 + 0]; r4.x = row[e0 + 0]; }
        if (nv > 1) { c4.y = col[e0 + 1]; r4.y = row[e0 + 1]; }
        if (nv > 2) { c4.z = col[e0 + 2]; r4.z = row[e0 + 2]; }
    }
    __syncthreads();                              // hist zeroed
    if (nv > 0) atomicAdd(&hist[c4.x >> 7], 1);
    if (nv > 1) atomicAdd(&hist[c4.y >> 7], 1);
    if (nv > 2) atomicAdd(&hist[c4.z >> 7], 1);
    if (nv > 3) atomicAdd(&hist[c4.w >> 7], 1);
    __syncthreads();
    for (int i = threadIdx.x; i < NB; i += BINTHREADS) {
        int h = hist[i];
        base[i] = h ? (i * CAP + atomicAdd(&cursor[i], h)) : 0;
        off[i] = 0;
    }
    __syncthreads();
    if (nv > 0) { int b = c4.x >> 7; int p = base[b] + atomicAdd(&off[b], 1);
                  if (p < (b + 1) * CAP) ebuf[p] = (r4.x << 7) | (c4.x & (NPB - 1)); }
    if (nv > 1) { int b = c4.y >> 7; int p = base[b] + atomicAdd(&off[b], 1);
                  if (p < (b + 1) * CAP) ebuf[p] = (r4.y << 7) | (c4.y & (NPB - 1)); }
    if (nv > 2) { int b = c4.z >> 7; int p = base[b] + atomicAdd(&off[b], 1);
                  if (p < (b + 1) * CAP) ebuf[p] = (r4.z << 7) | (c4.z & (NPB - 1)); }
    if (nv > 3) { int b = c4.w >> 7; int p = base[b] + atomicAdd(&off[b], 1);
                  if (p < (b + 1) * CAP) ebuf[p] = (r4.w << 7) | (c4.w & (NPB - 1)); }
}

// ---------------- FUSED phase B + layer-1 MFMA GEMM (256-thread blocks) ----------------
// One block per bucket (128 nodes), 4 waves: small barrier domains, ~3 blocks/CU,
// whole grid resident. ebuf loads issued unconditionally at entry (indices
// t+256k < 2048 < CAP are always in-bounds; poison masked by cnt predicate).
// MFMA A-fragments loaded directly from global x (2 float4 + cvt) -- no LDS tile.

__global__ __launch_bounds__(256) void phaseB_gemm1(
    const int* __restrict__ ebuf, const int* __restrict__ cursor,
    const float* __restrict__ x, const half_t* __restrict__ W1t,
    int2* __restrict__ rsc, int* __restrict__ csr_row,
    __half* __restrict__ hs1, int N)
{
    __shared__ int hist[NPB], cur[NPB];
    __shared__ int wtot;
    __shared__ float dv[NPB];
    int t = threadIdx.x;
    int b = blockIdx.x;
    int node0 = b << 7;
    int ebase = b * CAP;

    // ---- ebuf into registers immediately (8 independent loads in flight) ----
    int p[8];
    #pragma unroll
    for (int k = 0; k < 8; ++k) p[k] = ebuf[ebase + t + 256 * k];
    int cnt = min(cursor[b], CAP);            // uniform s_load, overlaps above
    if (t < NPB) hist[t] = 0;
    __syncthreads();
    #pragma unroll
    for (int k = 0; k < 8; ++k)
        if (t + 256 * k < cnt) atomicAdd(&hist[p[k] & (NPB - 1)], 1);
    if (cnt > 2048)                            // ~never (mean 2046, sigma ~45)
        for (int e = 2048 + t; e < cnt; e += 256)
            atomicAdd(&hist[ebuf[ebase + e] & (NPB - 1)], 1);
    __syncthreads();

    // ---- per-node exclusive scan (waves 0,1) ----
    int h = 0, incl = 0;
    if (t < NPB) {
        h = hist[t];
        incl = h;
        #pragma unroll
        for (int off = 1; off < 64; off <<= 1) {
            int u = __shfl_up(incl, off, 64);
            if ((t & 63) >= off) incl += u;
        }
        if (t == 63) wtot = incl;
    }
    __syncthreads();
    if (t < NPB) {
        if (t >= 64) incl += wtot;
        int start = ebase + incl - h;         // exclusive, absolute in region space
        cur[t] = start;
        dv[t] = rsqrtf((float)h + 1.0f);      // +1 = self-loop
        int n = node0 + t;
        if (n < N) rsc[n] = make_int2(start, h);
    }
    __syncthreads();                          // cur, dv ready

    // ---- csr fill from registers ----
    #pragma unroll
    for (int k = 0; k < 8; ++k)
        if (t + 256 * k < cnt) {
            int pos = atomicAdd(&cur[p[k] & (NPB - 1)], 1);
            csr_row[pos] = p[k] >> 7;
        }
    if (cnt > 2048)
        for (int e = 2048 + t; e < cnt; e += 256) {
            int pp = ebuf[ebase + e];
            int pos = atomicAdd(&cur[pp & (NPB - 1)], 1);
            csr_row[pos] = pp >> 7;
        }

    // ---- 128x64 MFMA GEMM, K=128: wave wv = m rows [32wv, 32wv+32) ----
    int wv = t >> 6, lane = t & 63;
    int l15 = lane & 15, quad = lane >> 4;
    int mbase = wv * 32;
    int r0 = min(node0 + mbase + l15, N - 1);        // clamped row (stores guarded)
    int r1 = min(node0 + mbase + 16 + l15, N - 1);
    const float* x0 = x + (size_t)r0 * F_IN;
    const float* x1 = x + (size_t)r1 * F_IN;
    float4v acc[2][4];
    #pragma unroll
    for (int mt = 0; mt < 2; ++mt)
        #pragma unroll
        for (int j = 0; j < 4; ++j) acc[mt][j] = (float4v){0.f, 0.f, 0.f, 0.f};
    #pragma unroll
    for (int kb = 0; kb < 4; ++kb) {
        int off = kb * 32 + quad * 8;
        float4 fa = *(const float4*)&x0[off];
        float4 fb = *(const float4*)&x0[off + 4];
        float4 ga = *(const float4*)&x1[off];
        float4 gb = *(const float4*)&x1[off + 4];
        half8 a0 = {(half_t)fa.x, (half_t)fa.y, (half_t)fa.z, (half_t)fa.w,
                    (half_t)fb.x, (half_t)fb.y, (half_t)fb.z, (half_t)fb.w};
        half8 a1 = {(half_t)ga.x, (half_t)ga.y, (half_t)ga.z, (half_t)ga.w,
                    (half_t)gb.x, (half_t)gb.y, (half_t)gb.z, (half_t)gb.w};
        #pragma unroll
        for (int j = 0; j < 4; ++j) {
            half8 bv = *(const half8*)&W1t[(size_t)(j * 16 + l15) * F_IN + off];
            acc[0][j] = __builtin_amdgcn_mfma_f32_16x16x32_f16(a0, bv, acc[0][j], 0, 0, 0);
            acc[1][j] = __builtin_amdgcn_mfma_f32_16x16x32_f16(a1, bv, acc[1][j], 0, 0, 0);
        }
    }
    // C/D: col(n) = l15, row(m) = quad*4 + r
    #pragma unroll
    for (int mt = 0; mt < 2; ++mt)
        #pragma unroll
        for (int j = 0; j < 4; ++j)
            #pragma unroll
            for (int r = 0; r < 4; ++r) {
                int m = mbase + mt * 16 + quad * 4 + r;
                int n = node0 + m;
                if (n < N) hs1[(size_t)n * HID + j * 16 + l15] =
                    __float2half(acc[mt][j][r] * dv[m]);
            }
}

// ---------------- layer-1 gather-aggregate + relu + @W2 ----------------
// 8 lanes per node (8 nodes/wave, 32/block). Lane owns 8 feats: one half8
// (16B) gather per edge. 8 predicated slots per iteration. dinv recomputed
// from count (no dinv array). W2 matvec via conflict-free LDS (stride 65).

__global__ __launch_bounds__(256) void agg_l1(
    const __half* __restrict__ hs1, const int2* __restrict__ rsc,
    const int* __restrict__ csr, const float* __restrict__ b1,
    const float* __restrict__ W2, __half* __restrict__ h2s, int N)
{
    __shared__ float W2l[HID * NCLS];     // 4 KB, index k*16+j
    __shared__ float o1[32][65];          // stride 65: wave's rows on distinct banks
    for (int i = threadIdx.x; i < HID * NCLS; i += 256) W2l[i] = W2[i];
    __syncthreads();
    int w = threadIdx.x >> 6, lane = threadIdx.x & 63;
    int g = lane >> 3, gl = lane & 7;
    int rowi = w * 8 + g;
    int c = blockIdx.x * 32 + rowi;
    bool active = (c < N);
    int cc = active ? c : 0;
    int2 rc = rsc[cc];
    int e0 = rc.x, e1 = rc.x + rc.y;
    int e1m1 = e1 - 1;
    float dc = rsqrtf((float)rc.y + 1.0f);
    const half8* H = (const half8*)hs1;   // 8 half8 per row
    half8 sv = H[(size_t)cc * 8 + gl];    // self-loop (hs1 pre-scaled by dinv[src])
    float sum[8];
    #pragma unroll
    for (int k = 0; k < 8; ++k) sum[k] = (float)sv[k];
    for (int i = e0; i < e1; i += 8) {
        int id[8];
        #pragma unroll
        for (int s = 0; s < 8; ++s) id[s] = csr[min(i + s, e1m1)];
        half8 a[8];
        #pragma unroll
        for (int s = 0; s < 8; ++s) a[s] = H[(size_t)id[s] * 8 + gl];
        #pragma unroll
        for (int s = 0; s < 8; ++s) {
            float fm = (i + s < e1) ? 1.f : 0.f;
            #pragma unroll
            for (int k = 0; k < 8; ++k) sum[k] = fmaf(fm, (float)a[s][k], sum[k]);
        }
    }
    float4 bb0 = *(const float4*)&b1[gl * 8];
    float4 bb1 = *(const float4*)&b1[gl * 8 + 4];
    o1[rowi][gl * 8 + 0] = fmaxf(fmaf(dc, sum[0], bb0.x), 0.f);
    o1[rowi][gl * 8 + 1] = fmaxf(fmaf(dc, sum[1], bb0.y), 0.f);
    o1[rowi][gl * 8 + 2] = fmaxf(fmaf(dc, sum[2], bb0.z), 0.f);
    o1[rowi][gl * 8 + 3] = fmaxf(fmaf(dc, sum[3], bb0.w), 0.f);
    o1[rowi][gl * 8 + 4] = fmaxf(fmaf(dc, sum[4], bb1.x), 0.f);
    o1[rowi][gl * 8 + 5] = fmaxf(fmaf(dc, sum[5], bb1.y), 0.f);
    o1[rowi][gl * 8 + 6] = fmaxf(fmaf(dc, sum[6], bb1.z), 0.f);
    o1[rowi][gl * 8 + 7] = fmaxf(fmaf(dc, sum[7], bb1.w), 0.f);
    // same-wave LDS write->read: no barrier needed.
    int j0 = gl * 2, j1 = gl * 2 + 1;
    float s0 = 0.f, s1 = 0.f;
    const float* orow = o1[rowi];
    #pragma unroll 8
    for (int k = 0; k < HID; ++k) {
        float ov = orow[k];
        s0 = fmaf(ov, W2l[k * NCLS + j0], s0);
        s1 = fmaf(ov, W2l[k * NCLS + j1], s1);
    }
    if (active) {
        __half2 hv;
        hv.x = __float2half(dc * s0);
        hv.y = __float2half(dc * s1);
        ((__half2*)h2s)[(size_t)c * 8 + gl] = hv;
    }
}

// ---------------- layer-2 gather-aggregate + log_softmax ----------------
// 8 lanes per node (8 nodes/wave, 32/block). Predicated 8-slot gather.

__global__ __launch_bounds__(256) void agg2_final(
    const __half* __restrict__ h2s, const int2* __restrict__ rsc,
    const int* __restrict__ csr, const float* __restrict__ b2,
    float* __restrict__ out, int N)
{
    int lane = threadIdx.x & 63;
    int g = lane >> 3, gl = lane & 7;
    int c = blockIdx.x * 32 + (threadIdx.x >> 6) * 8 + g;
    bool active = (c < N);
    int cc = active ? c : 0;
    int2 rc = rsc[cc];
    int e0 = rc.x, e1 = rc.x + rc.y;
    int e1m1 = e1 - 1;
    float dcv = rsqrtf((float)rc.y + 1.0f);
    const __half2* H = (const __half2*)h2s;  // 8 half2 per row
    float2 sum = __half22float2(H[(size_t)cc * 8 + gl]);  // self-loop
    for (int i = e0; i < e1; i += 8) {
        int id[8];
        #pragma unroll
        for (int s = 0; s < 8; ++s) id[s] = csr[min(i + s, e1m1)];
        __half2 a[8];
        #pragma unroll
        for (int s = 0; s < 8; ++s) a[s] = H[(size_t)id[s] * 8 + gl];
        #pragma unroll
        for (int s = 0; s < 8; ++s) {
            float fm = (i + s < e1) ? 1.f : 0.f;
            float2 f2 = __half22float2(a[s]);
            sum.x = fmaf(fm, f2.x, sum.x);
            sum.y = fmaf(fm, f2.y, sum.y);
        }
    }
    float2 bb = ((const float2*)b2)[gl];
    float2 v;
    v.x = fmaf(dcv, sum.x, bb.x);
    v.y = fmaf(dcv, sum.y, bb.y);
    float mx = fmaxf(v.x, v.y);
    mx = fmaxf(mx, __shfl_xor(mx, 1, 64));
    mx = fmaxf(mx, __shfl_xor(mx, 2, 64));
    mx = fmaxf(mx, __shfl_xor(mx, 4, 64));
    float s = __expf(v.x - mx) + __expf(v.y - mx);
    s += __shfl_xor(s, 1, 64);
    s += __shfl_xor(s, 2, 64);
    s += __shfl_xor(s, 4, 64);
    float lse = mx + __logf(s);
    if (active) ((float2*)out)[(size_t)c * 8 + gl] = make_float2(v.x - lse, v.y - lse);
}

// ---------------- launch ----------------

extern "C" void kernel_launch(void* const* d_in, const int* in_sizes, int n_in,
                              void* d_out, int out_size, void* d_ws, size_t ws_size,
                              hipStream_t stream) {
    const float* x  = (const float*)d_in[0];
    const int*   ei = (const int*)d_in[1];
    const float* W1 = (const float*)d_in[2];
    const float* b1 = (const float*)d_in[3];
    const float* W2 = (const float*)d_in[4];
    const float* b2 = (const float*)d_in[5];
    float* out = (float*)d_out;

    const int N = in_sizes[0] / F_IN;
    const int E = in_sizes[1] / 2;
    const int* row = ei;        // edge_index[0] = source
    const int* col = ei + E;    // edge_index[1] = destination

    const int NB = (N + NPB - 1) / NPB;          // buckets; must be <= 1024
    size_t Np  = ((size_t)N + 15) & ~(size_t)15;
    size_t NBp = ((size_t)NB + 15) & ~(size_t)15;
    size_t Rg  = (size_t)NB * CAP;               // capped region space (edge slots)

    char* p = (char*)d_ws;
    __half* hs1     = (__half*)p;  p += Np * HID * 2;
    __half* h2s     = (__half*)p;  p += Np * NCLS * 2;
    half_t* W1t     = (half_t*)p;  p += (size_t)F_IN * HID * 2;
    int2*   rsc     = (int2*)p;    p += Np * 8;       // per-node (start, count)
    int*    csr_row = (int*)p;     p += Rg * 4;
    int*    ebuf    = (int*)p;     p += Rg * 4;
    int*    cursor  = (int*)p;     p += NBp * 4;

    int nblkE = (E + CHUNK - 1) / CHUNK;

    hipMemsetAsync(cursor, 0, NBp * sizeof(int), stream);
    phaseA<<<nblkE + 1, BINTHREADS, 0, stream>>>(row, col, cursor, ebuf, E, NB, W1, W1t, nblkE);
    phaseB_gemm1<<<NB, 256, 0, stream>>>(ebuf, cursor, x, W1t, rsc, csr_row, hs1, N);
    agg_l1<<<(N + 31) / 32, 256, 0, stream>>>(hs1, rsc, csr_row, b1, W2, h2s, N);
    agg2_final<<<(N + 31) / 32, 256, 0, stream>>>(h2s, rsc, csr_row, b2, out, N);
}

// Round 14
// 183.699 us; speedup vs baseline: 1.0452x; 1.0452x over previous
//
#include <hip/hip_runtime.h>
#include <hip/hip_fp16.h>

#define F_IN 128
#define HID  64
#define NCLS 16
#define NPB  128      // nodes per bucket (pow2); bucket = col >> 7
#define CAP  4096     // edge slots reserved per bucket (2x mean 2046; ~45 sigma)
#define CHUNK 4096    // edges per phaseA block (= 4 * BINTHREADS exactly)
#define BINTHREADS 1024

typedef _Float16 half_t;
typedef __attribute__((ext_vector_type(8))) _Float16 half8;
typedef __attribute__((ext_vector_type(4))) float float4v;

// ---------------- phase A: bin edges into capped bucket regions + (fused) W1 prep ----------------

__global__ __launch_bounds__(BINTHREADS) void phaseA(
    const int* __restrict__ row, const int* __restrict__ col,
    int* __restrict__ cursor, int* __restrict__ ebuf, int E, int NB,
    const float* __restrict__ W1, half_t* __restrict__ W1t, int nblkE)
{
    if ((int)blockIdx.x >= nblkE) {               // W1 prep block
        for (int i = threadIdx.x; i < F_IN * HID; i += BINTHREADS) {
            int k = i >> 6, n = i & 63;
            W1t[n * F_IN + k] = (half_t)W1[i];
        }
        return;
    }
    __shared__ int hist[1024], base[1024], off[1024];   // NB <= 1024
    for (int i = threadIdx.x; i < NB; i += BINTHREADS) hist[i] = 0;
    int e0 = blockIdx.x * CHUNK + threadIdx.x * 4;
    int nv = min(max(E - e0, 0), 4);              // valid edges this thread
    int4 c4 = make_int4(0, 0, 0, 0), r4 = make_int4(0, 0, 0, 0);
    if (nv == 4) {                                // 16B-aligned fast path
        c4 = *(const int4*)&col[e0];
        r4 = *(const int4*)&row[e0];
    } else {
        if (nv > 0) { c4.x = col[e0 + 0]; r4.x = row[e0 + 0]; }
        if (nv > 1) { c4.y = col[e0 + 1]; r4.y = row[e0 + 1]; }
        if (nv > 2) { c4.z = col[e0 + 2]; r4.z = row[e0 + 2]; }
    }
    __syncthreads();                              // hist zeroed
    if (nv > 0) atomicAdd(&hist[c4.x >> 7], 1);
    if (nv > 1) atomicAdd(&hist[c4.y >> 7], 1);
    if (nv > 2) atomicAdd(&hist[c4.z >> 7], 1);
    if (nv > 3) atomicAdd(&hist[c4.w >> 7], 1);
    __syncthreads();
    for (int i = threadIdx.x; i < NB; i += BINTHREADS) {
        int h = hist[i];
        base[i] = h ? (i * CAP + atomicAdd(&cursor[i], h)) : 0;
        off[i] = 0;
    }
    __syncthreads();
    if (nv > 0) { int b = c4.x >> 7; int p = base[b] + atomicAdd(&off[b], 1);
                  if (p < (b + 1) * CAP) ebuf[p] = (r4.x << 7) | (c4.x & (NPB - 1)); }
    if (nv > 1) { int b = c4.y >> 7; int p = base[b] + atomicAdd(&off[b], 1);
                  if (p < (b + 1) * CAP) ebuf[p] = (r4.y << 7) | (c4.y & (NPB - 1)); }
    if (nv > 2) { int b = c4.z >> 7; int p = base[b] + atomicAdd(&off[b], 1);
                  if (p < (b + 1) * CAP) ebuf[p] = (r4.z << 7) | (c4.z & (NPB - 1)); }
    if (nv > 3) { int b = c4.w >> 7; int p = base[b] + atomicAdd(&off[b], 1);
                  if (p < (b + 1) * CAP) ebuf[p] = (r4.w << 7) | (c4.w & (NPB - 1)); }
}

// ---------------- ONE dispatch, two independent block families ----------------
// Blocks [0, NG):        MFMA GEMM for bucket b (recomputes its own degree hist
//                        from ebuf -- no scan/fill -- then 128x64 GEMM -> hs1).
// Blocks [NG, NG+NB):    CSR finalize for bucket b-NG (hist, shfl scan, rsc,
//                        csr_row fill). No cross-family dependency.

__global__ __launch_bounds__(256) void csr_gemm1(
    const int* __restrict__ ebuf, const int* __restrict__ cursor,
    const float* __restrict__ x, const half_t* __restrict__ W1t,
    int2* __restrict__ rsc, int* __restrict__ csr_row,
    __half* __restrict__ hs1, int N, int NG)
{
    __shared__ int hist[NPB];
    __shared__ float dv[NPB];
    int t = threadIdx.x;

    if ((int)blockIdx.x < NG) {
        // ================= GEMM family =================
        int b = blockIdx.x;
        int node0 = b << 7;
        int ebase = b * CAP;
        // degree hist (own copy; latency overlaps x loads below)
        int p[8];
        #pragma unroll
        for (int k = 0; k < 8; ++k) p[k] = ebuf[ebase + t + 256 * k];
        int cnt = min(cursor[b], CAP);
        if (t < NPB) hist[t] = 0;
        __syncthreads();
        #pragma unroll
        for (int k = 0; k < 8; ++k)
            if (t + 256 * k < cnt) atomicAdd(&hist[p[k] & (NPB - 1)], 1);
        if (cnt > 2048)
            for (int e = 2048 + t; e < cnt; e += 256)
                atomicAdd(&hist[ebuf[ebase + e] & (NPB - 1)], 1);
        __syncthreads();
        if (t < NPB) dv[t] = rsqrtf((float)hist[t] + 1.0f);   // +1 = self-loop
        __syncthreads();

        // 128x64 MFMA GEMM, K=128: wave wv = m rows [32wv, 32wv+32)
        int wv = t >> 6, lane = t & 63;
        int l15 = lane & 15, quad = lane >> 4;
        int mbase = wv * 32;
        int r0 = min(node0 + mbase + l15, N - 1);
        int r1 = min(node0 + mbase + 16 + l15, N - 1);
        const float* x0 = x + (size_t)r0 * F_IN;
        const float* x1 = x + (size_t)r1 * F_IN;
        float4v acc[2][4];
        #pragma unroll
        for (int mt = 0; mt < 2; ++mt)
            #pragma unroll
            for (int j = 0; j < 4; ++j) acc[mt][j] = (float4v){0.f, 0.f, 0.f, 0.f};
        #pragma unroll
        for (int kb = 0; kb < 4; ++kb) {
            int off = kb * 32 + quad * 8;
            float4 fa = *(const float4*)&x0[off];
            float4 fb = *(const float4*)&x0[off + 4];
            float4 ga = *(const float4*)&x1[off];
            float4 gb = *(const float4*)&x1[off + 4];
            half8 a0 = {(half_t)fa.x, (half_t)fa.y, (half_t)fa.z, (half_t)fa.w,
                        (half_t)fb.x, (half_t)fb.y, (half_t)fb.z, (half_t)fb.w};
            half8 a1 = {(half_t)ga.x, (half_t)ga.y, (half_t)ga.z, (half_t)ga.w,
                        (half_t)gb.x, (half_t)gb.y, (half_t)gb.z, (half_t)gb.w};
            #pragma unroll
            for (int j = 0; j < 4; ++j) {
                half8 bv = *(const half8*)&W1t[(size_t)(j * 16 + l15) * F_IN + off];
                acc[0][j] = __builtin_amdgcn_mfma_f32_16x16x32_f16(a0, bv, acc[0][j], 0, 0, 0);
                acc[1][j] = __builtin_amdgcn_mfma_f32_16x16x32_f16(a1, bv, acc[1][j], 0, 0, 0);
            }
        }
        // C/D: col(n) = l15, row(m) = quad*4 + r
        #pragma unroll
        for (int mt = 0; mt < 2; ++mt)
            #pragma unroll
            for (int j = 0; j < 4; ++j)
                #pragma unroll
                for (int r = 0; r < 4; ++r) {
                    int m = mbase + mt * 16 + quad * 4 + r;
                    int n = node0 + m;
                    if (n < N) hs1[(size_t)n * HID + j * 16 + l15] =
                        __float2half(acc[mt][j][r] * dv[m]);
                }
        return;
    }

    // ================= CSR family =================
    __shared__ int cur[NPB];
    __shared__ int wtot;
    int b = blockIdx.x - NG;
    int node0 = b << 7;
    int ebase = b * CAP;
    int p[8];
    #pragma unroll
    for (int k = 0; k < 8; ++k) p[k] = ebuf[ebase + t + 256 * k];
    int cnt = min(cursor[b], CAP);
    if (t < NPB) hist[t] = 0;
    __syncthreads();
    #pragma unroll
    for (int k = 0; k < 8; ++k)
        if (t + 256 * k < cnt) atomicAdd(&hist[p[k] & (NPB - 1)], 1);
    if (cnt > 2048)
        for (int e = 2048 + t; e < cnt; e += 256)
            atomicAdd(&hist[ebuf[ebase + e] & (NPB - 1)], 1);
    __syncthreads();
    int h = 0, incl = 0;
    if (t < NPB) {                         // waves 0,1 fully active
        h = hist[t];
        incl = h;
        #pragma unroll
        for (int off = 1; off < 64; off <<= 1) {
            int u = __shfl_up(incl, off, 64);
            if ((t & 63) >= off) incl += u;
        }
        if (t == 63) wtot = incl;
    }
    __syncthreads();
    if (t < NPB) {
        if (t >= 64) incl += wtot;
        int start = ebase + incl - h;      // exclusive, absolute in region space
        cur[t] = start;
        int n = node0 + t;
        if (n < N) rsc[n] = make_int2(start, h);
    }
    __syncthreads();
    #pragma unroll
    for (int k = 0; k < 8; ++k)
        if (t + 256 * k < cnt) {
            int pos = atomicAdd(&cur[p[k] & (NPB - 1)], 1);
            csr_row[pos] = p[k] >> 7;
        }
    if (cnt > 2048)
        for (int e = 2048 + t; e < cnt; e += 256) {
            int pp = ebuf[ebase + e];
            int pos = atomicAdd(&cur[pp & (NPB - 1)], 1);
            csr_row[pos] = pp >> 7;
        }
}

// ---------------- layer-1 gather-aggregate + relu + @W2 ----------------
// 8 lanes per node (8 nodes/wave, 32/block). Lane owns 8 feats: one half8
// (16B) gather per edge. 8 predicated slots per iteration. dinv recomputed
// from count. W2 matvec via conflict-free LDS (stride 65).

__global__ __launch_bounds__(256) void agg_l1(
    const __half* __restrict__ hs1, const int2* __restrict__ rsc,
    const int* __restrict__ csr, const float* __restrict__ b1,
    const float* __restrict__ W2, __half* __restrict__ h2s, int N)
{
    __shared__ float W2l[HID * NCLS];     // 4 KB, index k*16+j
    __shared__ float o1[32][65];          // stride 65: wave's rows on distinct banks
    for (int i = threadIdx.x; i < HID * NCLS; i += 256) W2l[i] = W2[i];
    __syncthreads();
    int w = threadIdx.x >> 6, lane = threadIdx.x & 63;
    int g = lane >> 3, gl = lane & 7;
    int rowi = w * 8 + g;
    int c = blockIdx.x * 32 + rowi;
    bool active = (c < N);
    int cc = active ? c : 0;
    int2 rc = rsc[cc];
    int e0 = rc.x, e1 = rc.x + rc.y;
    int e1m1 = e1 - 1;
    float dc = rsqrtf((float)rc.y + 1.0f);
    const half8* H = (const half8*)hs1;   // 8 half8 per row
    half8 sv = H[(size_t)cc * 8 + gl];    // self-loop (hs1 pre-scaled by dinv[src])
    float sum[8];
    #pragma unroll
    for (int k = 0; k < 8; ++k) sum[k] = (float)sv[k];
    for (int i = e0; i < e1; i += 8) {
        int id[8];
        #pragma unroll
        for (int s = 0; s < 8; ++s) id[s] = csr[min(i + s, e1m1)];
        half8 a[8];
        #pragma unroll
        for (int s = 0; s < 8; ++s) a[s] = H[(size_t)id[s] * 8 + gl];
        #pragma unroll
        for (int s = 0; s < 8; ++s) {
            float fm = (i + s < e1) ? 1.f : 0.f;
            #pragma unroll
            for (int k = 0; k < 8; ++k) sum[k] = fmaf(fm, (float)a[s][k], sum[k]);
        }
    }
    float4 bb0 = *(const float4*)&b1[gl * 8];
    float4 bb1 = *(const float4*)&b1[gl * 8 + 4];
    o1[rowi][gl * 8 + 0] = fmaxf(fmaf(dc, sum[0], bb0.x), 0.f);
    o1[rowi][gl * 8 + 1] = fmaxf(fmaf(dc, sum[1], bb0.y), 0.f);
    o1[rowi][gl * 8 + 2] = fmaxf(fmaf(dc, sum[2], bb0.z), 0.f);
    o1[rowi][gl * 8 + 3] = fmaxf(fmaf(dc, sum[3], bb0.w), 0.f);
    o1[rowi][gl * 8 + 4] = fmaxf(fmaf(dc, sum[4], bb1.x), 0.f);
    o1[rowi][gl * 8 + 5] = fmaxf(fmaf(dc, sum[5], bb1.y), 0.f);
    o1[rowi][gl * 8 + 6] = fmaxf(fmaf(dc, sum[6], bb1.z), 0.f);
    o1[rowi][gl * 8 + 7] = fmaxf(fmaf(dc, sum[7], bb1.w), 0.f);
    // same-wave LDS write->read: no barrier needed.
    int j0 = gl * 2, j1 = gl * 2 + 1;
    float s0 = 0.f, s1 = 0.f;
    const float* orow = o1[rowi];
    #pragma unroll 8
    for (int k = 0; k < HID; ++k) {
        float ov = orow[k];
        s0 = fmaf(ov, W2l[k * NCLS + j0], s0);
        s1 = fmaf(ov, W2l[k * NCLS + j1], s1);
    }
    if (active) {
        __half2 hv;
        hv.x = __float2half(dc * s0);
        hv.y = __float2half(dc * s1);
        ((__half2*)h2s)[(size_t)c * 8 + gl] = hv;
    }
}

// ---------------- layer-2 gather-aggregate + log_softmax ----------------

__global__ __launch_bounds__(256) void agg2_final(
    const __half* __restrict__ h2s, const int2* __restrict__ rsc,
    const int* __restrict__ csr, const float* __restrict__ b2,
    float* __restrict__ out, int N)
{
    int lane = threadIdx.x & 63;
    int g = lane >> 3, gl = lane & 7;
    int c = blockIdx.x * 32 + (threadIdx.x >> 6) * 8 + g;
    bool active = (c < N);
    int cc = active ? c : 0;
    int2 rc = rsc[cc];
    int e0 = rc.x, e1 = rc.x + rc.y;
    int e1m1 = e1 - 1;
    float dcv = rsqrtf((float)rc.y + 1.0f);
    const __half2* H = (const __half2*)h2s;  // 8 half2 per row
    float2 sum = __half22float2(H[(size_t)cc * 8 + gl]);  // self-loop
    for (int i = e0; i < e1; i += 8) {
        int id[8];
        #pragma unroll
        for (int s = 0; s < 8; ++s) id[s] = csr[min(i + s, e1m1)];
        __half2 a[8];
        #pragma unroll
        for (int s = 0; s < 8; ++s) a[s] = H[(size_t)id[s] * 8 + gl];
        #pragma unroll
        for (int s = 0; s < 8; ++s) {
            float fm = (i + s < e1) ? 1.f : 0.f;
            float2 f2 = __half22float2(a[s]);
            sum.x = fmaf(fm, f2.x, sum.x);
            sum.y = fmaf(fm, f2.y, sum.y);
        }
    }
    float2 bb = ((const float2*)b2)[gl];
    float2 v;
    v.x = fmaf(dcv, sum.x, bb.x);
    v.y = fmaf(dcv, sum.y, bb.y);
    float mx = fmaxf(v.x, v.y);
    mx = fmaxf(mx, __shfl_xor(mx, 1, 64));
    mx = fmaxf(mx, __shfl_xor(mx, 2, 64));
    mx = fmaxf(mx, __shfl_xor(mx, 4, 64));
    float s = __expf(v.x - mx) + __expf(v.y - mx);
    s += __shfl_xor(s, 1, 64);
    s += __shfl_xor(s, 2, 64);
    s += __shfl_xor(s, 4, 64);
    float lse = mx + __logf(s);
    if (active) ((float2*)out)[(size_t)c * 8 + gl] = make_float2(v.x - lse, v.y - lse);
}

// ---------------- launch ----------------

extern "C" void kernel_launch(void* const* d_in, const int* in_sizes, int n_in,
                              void* d_out, int out_size, void* d_ws, size_t ws_size,
                              hipStream_t stream) {
    const float* x  = (const float*)d_in[0];
    const int*   ei = (const int*)d_in[1];
    const float* W1 = (const float*)d_in[2];
    const float* b1 = (const float*)d_in[3];
    const float* W2 = (const float*)d_in[4];
    const float* b2 = (const float*)d_in[5];
    float* out = (float*)d_out;

    const int N = in_sizes[0] / F_IN;
    const int E = in_sizes[1] / 2;
    const int* row = ei;        // edge_index[0] = source
    const int* col = ei + E;    // edge_index[1] = destination

    const int NB = (N + NPB - 1) / NPB;          // buckets; must be <= 1024
    size_t Np  = ((size_t)N + 15) & ~(size_t)15;
    size_t NBp = ((size_t)NB + 15) & ~(size_t)15;
    size_t Rg  = (size_t)NB * CAP;               // capped region space (edge slots)

    char* p = (char*)d_ws;
    __half* hs1     = (__half*)p;  p += Np * HID * 2;
    __half* h2s     = (__half*)p;  p += Np * NCLS * 2;
    half_t* W1t     = (half_t*)p;  p += (size_t)F_IN * HID * 2;
    int2*   rsc     = (int2*)p;    p += Np * 8;       // per-node (start, count)
    int*    csr_row = (int*)p;     p += Rg * 4;
    int*    ebuf    = (int*)p;     p += Rg * 4;
    int*    cursor  = (int*)p;     p += NBp * 4;

    int nblkE = (E + CHUNK - 1) / CHUNK;

    hipMemsetAsync(cursor, 0, NBp * sizeof(int), stream);
    phaseA<<<nblkE + 1, BINTHREADS, 0, stream>>>(row, col, cursor, ebuf, E, NB, W1, W1t, nblkE);
    csr_gemm1<<<2 * NB, 256, 0, stream>>>(ebuf, cursor, x, W1t, rsc, csr_row, hs1, N, NB);
    agg_l1<<<(N + 31) / 32, 256, 0, stream>>>(hs1, rsc, csr_row, b1, W2, h2s, N);
    agg2_final<<<(N + 31) / 32, 256, 0, stream>>>(h2s, rsc, csr_row, b2, out, N);
}